// Round 12
// baseline (691.615 us; speedup 1.0000x reference)
//
#include <hip/hip_runtime.h>

#define N_PTS 131072
#define KC    512
#define DIM   64
#define MAXIT 5
#define NCHUNK 64
#define CHUNK_PTS (N_PTS / NCHUNK)    // 2048
#define FIXSCALE 1099511627776.0      // 2^40

typedef short v8s __attribute__((ext_vector_type(8)));
typedef float v4f __attribute__((ext_vector_type(4)));

// f32 -> bf16 bits, RTNE (normals; inputs are O(1) gaussians + residuals)
__device__ __forceinline__ unsigned short bf16_rtne(float x) {
    unsigned int u = __float_as_uint(x);
    return (unsigned short)((u + 0x7FFFu + ((u >> 16) & 1u)) >> 16);
}
__device__ __forceinline__ float bf16_f32(unsigned short b) {
    return __uint_as_float(((unsigned int)b) << 16);
}
// 3-way split: x == h + m + l exactly (24 mantissa bits captured)
__device__ __forceinline__ void split3(float x, short& h, short& m, short& l) {
    unsigned short hb = bf16_rtne(x);
    float r1 = x - bf16_f32(hb);
    unsigned short mb = bf16_rtne(r1);
    float r2 = r1 - bf16_f32(mb);
    h = (short)hb; m = (short)mb; l = (short)bf16_rtne(r2);
}

// ---------------------------------------------------------------------------
// prep (iter 0): c2[k] (round-2 tree, bit-identical) + 3-way bf16 split of C0.
// ---------------------------------------------------------------------------
__global__ __launch_bounds__(256) void prep_kernel(
        const float* __restrict__ C, float* __restrict__ c2out,
        unsigned short* __restrict__ Ch, unsigned short* __restrict__ Cm,
        unsigned short* __restrict__ Cl) {
    int k = blockIdx.x * 256 + threadIdx.x;
    if (k < KC) {
        float sq[DIM];
        #pragma unroll
        for (int j = 0; j < DIM; ++j) {
            float c = C[k * DIM + j];
            sq[j] = c * c;
            short h, m, l;
            split3(c, h, m, l);
            Ch[k * DIM + j] = (unsigned short)h;
            Cm[k * DIM + j] = (unsigned short)m;
            Cl[k * DIM + j] = (unsigned short)l;
        }
        #pragma unroll
        for (int st = 1; st < DIM; st <<= 1)
            #pragma unroll
            for (int j = 0; j < DIM; j += 2 * st)
                sq[j] = sq[j] + sq[j + st];
        c2out[k] = sq[0];
    }
}

// ---------------------------------------------------------------------------
// assign kernel, ROUND 12: round-11 MFMA pipeline rebalanced for occupancy.
// T=2 (32 pts/wave) + register prefetch: ~150 unified regs/wave -> 3
// waves/SIMD (round 11's T=4+prefetch needed ~230-260 -> 1-2 waves/SIMD,
// occupancy 10.6%, MfmaUtil 22% — latency fully exposed). Grid 1024 blocks
// (4 blocks/CU candidates, residency VGPR-capped at 3).
// __launch_bounds__(256,3): pin the 3-waves/EU bucket (cap ~170 regs).
// MFMA order, x2/c2 trees, d2 epilogue, argmin: verbatim rounds 10/11
// (passed twice, bit-identical numerics).
// ---------------------------------------------------------------------------
__global__ __launch_bounds__(256, 3) void assign_kernel(
        const float* __restrict__ X,
        const unsigned short* __restrict__ Ch,
        const unsigned short* __restrict__ Cm,
        const unsigned short* __restrict__ Cl,
        const float* __restrict__ c2v, float* __restrict__ out_f) {
    __shared__ float x2p[4][2][16][8];   // 4 KB
    __shared__ float x2f[4][2][16];      // 0.5 KB

    const int wv  = threadIdx.x >> 6;
    const int l   = threadIdx.x & 63;
    const int row = l & 15;       // A: point-in-tile; B: center-in-tile (D col)
    const int q   = l >> 4;       // k-quad; D rows = q*4+r
    const int pbase = blockIdx.x * 128 + wv * 32;

    // ---- A fragments (3 splits x 2 k-chunks x 2 point-tiles) + x2 partials
    v8s ah[2][2], am[2][2], al[2][2];
    #pragma unroll
    for (int T = 0; T < 2; ++T) {
        const float* xr = X + (size_t)(pbase + T * 16 + row) * DIM + q * 8;
        #pragma unroll
        for (int kc = 0; kc < 2; ++kc) {
            float4 v0 = *(const float4*)(xr + kc * 32);
            float4 v1 = *(const float4*)(xr + kc * 32 + 4);
            float e[8] = { v0.x, v0.y, v0.z, v0.w, v1.x, v1.y, v1.z, v1.w };
            v8s H, M, L;
            #pragma unroll
            for (int j = 0; j < 8; ++j) {
                short hh, mm, ll;
                split3(e[j], hh, mm, ll);
                H[j] = hh; M[j] = mm; L[j] = ll;
            }
            ah[T][kc] = H; am[T][kc] = M; al[T][kc] = L;
            // aligned 8-leaf subtree of the round-2 x2 tree (exact order)
            float s0 = e[0]*e[0], s1 = e[1]*e[1], s2 = e[2]*e[2], s3 = e[3]*e[3];
            float s4 = e[4]*e[4], s5 = e[5]*e[5], s6 = e[6]*e[6], s7 = e[7]*e[7];
            x2p[wv][T][row][kc * 4 + q] =
                ((s0 + s1) + (s2 + s3)) + ((s4 + s5) + (s6 + s7));
        }
    }
    __syncthreads();
    if (threadIdx.x < 128) {   // 4 waves x 2 T x 16 rows (same tree as r2-r11)
        int w2 = threadIdx.x >> 5, T2 = (threadIdx.x >> 4) & 1, pt = threadIdx.x & 15;
        const float* P = x2p[w2][T2][pt];
        x2f[w2][T2][pt] = ((P[0] + P[1]) + (P[2] + P[3]))
                        + ((P[4] + P[5]) + (P[6] + P[7]));
    }
    __syncthreads();
    float x2x[2][4];
    #pragma unroll
    for (int T = 0; T < 2; ++T)
        #pragma unroll
        for (int r = 0; r < 4; ++r)
            x2x[T][r] = x2f[wv][T][q * 4 + r];

    float bd[2][4];
    int   bk[2][4];
    #pragma unroll
    for (int T = 0; T < 2; ++T)
        #pragma unroll
        for (int r = 0; r < 4; ++r) { bd[T][r] = 3.4e38f; bk[T][r] = 0; }

    // ---- prefetch center-tile 0 into registers
    v8s nbh0, nbh1, nbm0, nbm1, nbl0, nbl1;
    float nc2k;
    {
        const size_t cb = (size_t)row * DIM + q * 8;
        nbh0 = *(const v8s*)(Ch + cb);
        nbh1 = *(const v8s*)(Ch + cb + 32);
        nbm0 = *(const v8s*)(Cm + cb);
        nbm1 = *(const v8s*)(Cm + cb + 32);
        nbl0 = *(const v8s*)(Cl + cb);
        nbl1 = *(const v8s*)(Cl + cb + 32);
        nc2k = c2v[row];
    }

    // ---- main loop over 32 center-tiles, register double-buffered
    for (int ct = 0; ct < 32; ++ct) {
        v8s bh0 = nbh0, bh1 = nbh1, bm0 = nbm0, bm1 = nbm1,
            bl0 = nbl0, bl1 = nbl1;
        float c2k = nc2k;
        {   // prefetch ct+1 (wraps to 0 on last iter: in-bounds, unused)
            int ctn = (ct + 1) & 31;
            const size_t cb = (size_t)(ctn * 16 + row) * DIM + q * 8;
            nbh0 = *(const v8s*)(Ch + cb);
            nbh1 = *(const v8s*)(Ch + cb + 32);
            nbm0 = *(const v8s*)(Cm + cb);
            nbm1 = *(const v8s*)(Cm + cb + 32);
            nbl0 = *(const v8s*)(Cl + cb);
            nbl1 = *(const v8s*)(Cl + cb + 32);
            nc2k = c2v[ctn * 16 + row];
        }

        #pragma unroll
        for (int T = 0; T < 2; ++T) {
            v4f acc = {0.f, 0.f, 0.f, 0.f};
            acc = __builtin_amdgcn_mfma_f32_16x16x32_bf16(ah[T][0], bh0, acc, 0, 0, 0);
            acc = __builtin_amdgcn_mfma_f32_16x16x32_bf16(ah[T][1], bh1, acc, 0, 0, 0);
            acc = __builtin_amdgcn_mfma_f32_16x16x32_bf16(am[T][0], bh0, acc, 0, 0, 0);
            acc = __builtin_amdgcn_mfma_f32_16x16x32_bf16(am[T][1], bh1, acc, 0, 0, 0);
            acc = __builtin_amdgcn_mfma_f32_16x16x32_bf16(ah[T][0], bm0, acc, 0, 0, 0);
            acc = __builtin_amdgcn_mfma_f32_16x16x32_bf16(ah[T][1], bm1, acc, 0, 0, 0);
            acc = __builtin_amdgcn_mfma_f32_16x16x32_bf16(am[T][0], bm0, acc, 0, 0, 0);
            acc = __builtin_amdgcn_mfma_f32_16x16x32_bf16(am[T][1], bm1, acc, 0, 0, 0);
            acc = __builtin_amdgcn_mfma_f32_16x16x32_bf16(al[T][0], bh0, acc, 0, 0, 0);
            acc = __builtin_amdgcn_mfma_f32_16x16x32_bf16(al[T][1], bh1, acc, 0, 0, 0);
            acc = __builtin_amdgcn_mfma_f32_16x16x32_bf16(ah[T][0], bl0, acc, 0, 0, 0);
            acc = __builtin_amdgcn_mfma_f32_16x16x32_bf16(ah[T][1], bl1, acc, 0, 0, 0);
            #pragma unroll
            for (int r = 0; r < 4; ++r) {
                float tt = x2x[T][r] + c2k;
                float d2 = fmaf(-2.0f, acc[r], tt);
                if (d2 < bd[T][r]) { bd[T][r] = d2; bk[T][r] = ct * 16 + row; }
            }
        }
    }

    // ---- cross-lane argmin over the 16 center residues (lane bits 0..3)
    #pragma unroll
    for (int T = 0; T < 2; ++T)
        #pragma unroll
        for (int r = 0; r < 4; ++r) {
            unsigned int b = __float_as_uint(bd[T][r]);
            b = (b & 0x80000000u) ? ~b : (b | 0x80000000u);
            unsigned long long key = ((unsigned long long)b << 32)
                                   | (unsigned int)bk[T][r];
            #pragma unroll
            for (int st = 1; st <= 8; st <<= 1) {
                unsigned long long o = __shfl_xor(key, st, 64);
                if (o < key) key = o;
            }
            if (row == 0) {
                int p = pbase + T * 16 + q * 4 + r;
                out_f[p] = (float)((int)(unsigned int)key);
            }
        }
}

// ---------------------------------------------------------------------------
// accumulate: 256 blocks = 64 chunks x 4 dim-slices. INT64 fixed-point LDS +
// global atomics (order-independent -> bit-deterministic, round-5 proven).
// ---------------------------------------------------------------------------
__global__ __launch_bounds__(256) void accum_kernel(
        const float* __restrict__ X, const float* __restrict__ af,
        unsigned long long* __restrict__ qsums, int* __restrict__ counts) {
    __shared__ unsigned long long lsum[KC * 16];   // 64 KB
    __shared__ int lcnt[KC];
    int slice = blockIdx.x & 3;
    int chunk = blockIdx.x >> 2;
    int p4 = threadIdx.x >> 2;
    int c4 = threadIdx.x & 3;

    for (int i = threadIdx.x; i < KC * 16; i += 256) lsum[i] = 0ull;
    for (int i = threadIdx.x; i < KC; i += 256) lcnt[i] = 0;
    __syncthreads();

    int base = chunk * CHUNK_PTS;
    #pragma unroll 2
    for (int it = 0; it < CHUNK_PTS / 64; ++it) {
        int n = base + it * 64 + p4;
        int a = (int)af[n];
        float4 xv = *(const float4*)(X + (size_t)n * DIM + slice * 16 + c4 * 4);
        long long q0 = (long long)llrint((double)xv.x * FIXSCALE);
        long long q1 = (long long)llrint((double)xv.y * FIXSCALE);
        long long q2 = (long long)llrint((double)xv.z * FIXSCALE);
        long long q3 = (long long)llrint((double)xv.w * FIXSCALE);
        atomicAdd(&lsum[a * 16 + c4 * 4 + 0], (unsigned long long)q0);
        atomicAdd(&lsum[a * 16 + c4 * 4 + 1], (unsigned long long)q1);
        atomicAdd(&lsum[a * 16 + c4 * 4 + 2], (unsigned long long)q2);
        atomicAdd(&lsum[a * 16 + c4 * 4 + 3], (unsigned long long)q3);
        if (slice == 0 && c4 == 0) atomicAdd(&lcnt[a], 1);
    }
    __syncthreads();

    for (int i = threadIdx.x; i < KC * 16; i += 256) {
        unsigned long long v = lsum[i];
        if (v != 0ull)
            atomicAdd(&qsums[(i >> 4) * DIM + slice * 16 + (i & 15)], v);
    }
    if (slice == 0)
        for (int i = threadIdx.x; i < KC; i += 256) {
            int v = lcnt[i];
            if (v != 0) atomicAdd(&counts[i], v);
        }
}

// ---------------------------------------------------------------------------
// update: centers = sums/max(cnt,1), ==0 -> re-seed; writes f32 centers to
// d_out tail, next iter's c2 (same butterfly tree) + 3-way bf16 splits.
// ---------------------------------------------------------------------------
__global__ __launch_bounds__(256) void update_kernel(
        const unsigned long long* __restrict__ qsums,
        const int* __restrict__ counts,
        const int* __restrict__ repl, const float* __restrict__ X,
        float* __restrict__ outC, float* __restrict__ c2v,
        unsigned short* __restrict__ Ch, unsigned short* __restrict__ Cm,
        unsigned short* __restrict__ Cl) {
    int k = blockIdx.x * 4 + (threadIdx.x >> 6);
    int d = threadIdx.x & 63;

    long long qq = (long long)qsums[k * DIM + d];
    float s = (float)((double)qq * (1.0 / FIXSCALE));
    float cnt = (float)counts[k];
    float v = s / fmaxf(cnt, 1.0f);
    if (v == 0.0f) v = X[(size_t)repl[k] * DIM + d];
    outC[k * DIM + d] = v;

    short h, m, l;
    split3(v, h, m, l);
    Ch[k * DIM + d] = (unsigned short)h;
    Cm[k * DIM + d] = (unsigned short)m;
    Cl[k * DIM + d] = (unsigned short)l;

    float sq = v * v;
    #pragma unroll
    for (int st = 1; st < 64; st <<= 1)
        sq += __shfl_xor(sq, st, 64);
    if (d == 0) c2v[k] = sq;
}

// ---------------------------------------------------------------------------
extern "C" void kernel_launch(void* const* d_in, const int* in_sizes, int n_in,
                              void* d_out, int out_size, void* d_ws, size_t ws_size,
                              hipStream_t stream) {
    const float* X    = (const float*)d_in[0];   // [N, D]
    const float* C0   = (const float*)d_in[1];   // [K, D]
    const int*   repl = (const int*)d_in[2];     // [MAXIT, K]
    float* out = (float*)d_out;                  // [N] assignments + [K*D] centers

    // ws: 452 KB total (round-2's 920 KB proved safe; round-3's 12.8 MB not).
    char* ws = (char*)d_ws;
    unsigned short* Ch = (unsigned short*)(ws + 0);            // 64 KB
    unsigned short* Cm = (unsigned short*)(ws + (64 << 10));   // 64 KB
    unsigned short* Cl = (unsigned short*)(ws + (128 << 10));  // 64 KB
    unsigned long long* qsums = (unsigned long long*)(ws + (192 << 10)); // 256 KB
    int*   counts = (int*)  (ws + (448 << 10));                // 2 KB
    float* c2v    = (float*)(ws + (450 << 10));                // 2 KB

    prep_kernel<<<2, 256, 0, stream>>>(C0, c2v, Ch, Cm, Cl);

    for (int i = 0; i < MAXIT; ++i) {
        assign_kernel<<<N_PTS / 128, 256, 0, stream>>>(
            X, Ch, Cm, Cl, c2v, out);

        hipMemsetAsync(qsums, 0, KC * DIM * sizeof(unsigned long long)
                                 + KC * sizeof(int), stream);

        accum_kernel<<<NCHUNK * 4, 256, 0, stream>>>(X, out, qsums, counts);

        update_kernel<<<KC / 4, 256, 0, stream>>>(
            qsums, counts, repl + i * KC, X, out + N_PTS, c2v, Ch, Cm, Cl);
    }
}

// Round 13
// 474.556 us; speedup vs baseline: 1.4574x; 1.4574x over previous
//
#include <hip/hip_runtime.h>

#define N_PTS 131072
#define KC    512
#define DIM   64
#define MAXIT 5
#define NCHUNK 64
#define CHUNK_PTS (N_PTS / NCHUNK)    // 2048
#define FIXSCALE 1099511627776.0      // 2^40

typedef short v8s __attribute__((ext_vector_type(8)));
typedef float v4f __attribute__((ext_vector_type(4)));

// f32 -> bf16 bits, RTNE (normals; inputs are O(1) gaussians + residuals)
__device__ __forceinline__ unsigned short bf16_rtne(float x) {
    unsigned int u = __float_as_uint(x);
    return (unsigned short)((u + 0x7FFFu + ((u >> 16) & 1u)) >> 16);
}
__device__ __forceinline__ float bf16_f32(unsigned short b) {
    return __uint_as_float(((unsigned int)b) << 16);
}
// 3-way split: x == h + m + l exactly (24 mantissa bits captured)
__device__ __forceinline__ void split3(float x, short& h, short& m, short& l) {
    unsigned short hb = bf16_rtne(x);
    float r1 = x - bf16_f32(hb);
    unsigned short mb = bf16_rtne(r1);
    float r2 = r1 - bf16_f32(mb);
    h = (short)hb; m = (short)mb; l = (short)bf16_rtne(r2);
}

// ---------------------------------------------------------------------------
// prep (iter 0): c2[k] (round-2 tree, bit-identical) + 3-way bf16 split of C0.
// ---------------------------------------------------------------------------
__global__ __launch_bounds__(256) void prep_kernel(
        const float* __restrict__ C, float* __restrict__ c2out,
        unsigned short* __restrict__ Ch, unsigned short* __restrict__ Cm,
        unsigned short* __restrict__ Cl) {
    int k = blockIdx.x * 256 + threadIdx.x;
    if (k < KC) {
        float sq[DIM];
        #pragma unroll
        for (int j = 0; j < DIM; ++j) {
            float c = C[k * DIM + j];
            sq[j] = c * c;
            short h, m, l;
            split3(c, h, m, l);
            Ch[k * DIM + j] = (unsigned short)h;
            Cm[k * DIM + j] = (unsigned short)m;
            Cl[k * DIM + j] = (unsigned short)l;
        }
        #pragma unroll
        for (int st = 1; st < DIM; st <<= 1)
            #pragma unroll
            for (int j = 0; j < DIM; j += 2 * st)
                sq[j] = sq[j] + sq[j + st];
        c2out[k] = sq[0];
    }
}

// ---------------------------------------------------------------------------
// assign kernel, ROUND 13: bf16-split MFMA with BLOCK-SHARED LDS-staged B.
// All 4 waves consume the same center-tile -> stage its 6 KB (3 splits x
// 2 kc x 64 lanes x 16 B, fragment-ordered) into LDS once per block via the
// m97 2-barrier pipeline: barrier / ds_write(regs) / gload ct+1 -> regs /
// barrier / ds_read+MFMA. The ds_write-before-barrier anchors the prefetch
// (rounds 9/11/12 showed the compiler sinks register-only prefetch; it
// cannot move a load past the ds_write that consumes it). 4x less L2
// traffic; in-flight time per load = one full GEMM (~500 cyc > ~300 L2).
// Consumer ds_read_b128 at base+lane*16: conflict-free.
// MFMA order, x2/c2 trees, d2 epilogue, argmin: verbatim r10-r12 (passed
// 3x, bit-identical numerics — B bits just route through LDS).
// ---------------------------------------------------------------------------
__global__ __launch_bounds__(256, 4) void assign_kernel(
        const float* __restrict__ X,
        const unsigned short* __restrict__ Ch,
        const unsigned short* __restrict__ Cm,
        const unsigned short* __restrict__ Cl,
        const float* __restrict__ c2v, float* __restrict__ out_f) {
    __shared__ short Bt[6 * 64 * 8];     // 6 KB: 6 segments x 64 lanes x v8s
    __shared__ float c2t[KC];            // 2 KB
    __shared__ float x2p[4][2][16][8];   // 4 KB
    __shared__ float x2f[4][2][16];      // 0.5 KB

    const int t   = threadIdx.x;
    const int wv  = t >> 6;
    const int l   = t & 63;
    const int row = l & 15;       // A: point-in-tile; B: center-in-tile (D col)
    const int q   = l >> 4;       // k-quad; D rows = q*4+r
    const int pbase = blockIdx.x * 128 + wv * 32;

    // stage c2 into LDS once (consumed after the loop's barriers)
    for (int i = t; i < KC; i += 256) c2t[i] = c2v[i];

    // ---- A fragments (3 splits x 2 k-chunks x 2 point-tiles) + x2 partials
    v8s ah[2][2], am[2][2], al[2][2];
    #pragma unroll
    for (int T = 0; T < 2; ++T) {
        const float* xr = X + (size_t)(pbase + T * 16 + row) * DIM + q * 8;
        #pragma unroll
        for (int kc = 0; kc < 2; ++kc) {
            float4 v0 = *(const float4*)(xr + kc * 32);
            float4 v1 = *(const float4*)(xr + kc * 32 + 4);
            float e[8] = { v0.x, v0.y, v0.z, v0.w, v1.x, v1.y, v1.z, v1.w };
            v8s H, M, L;
            #pragma unroll
            for (int j = 0; j < 8; ++j) {
                short hh, mm, ll;
                split3(e[j], hh, mm, ll);
                H[j] = hh; M[j] = mm; L[j] = ll;
            }
            ah[T][kc] = H; am[T][kc] = M; al[T][kc] = L;
            // aligned 8-leaf subtree of the round-2 x2 tree (exact order)
            float s0 = e[0]*e[0], s1 = e[1]*e[1], s2 = e[2]*e[2], s3 = e[3]*e[3];
            float s4 = e[4]*e[4], s5 = e[5]*e[5], s6 = e[6]*e[6], s7 = e[7]*e[7];
            x2p[wv][T][row][kc * 4 + q] =
                ((s0 + s1) + (s2 + s3)) + ((s4 + s5) + (s6 + s7));
        }
    }
    __syncthreads();
    if (t < 128) {   // 4 waves x 2 T x 16 rows (same tree as r2-r12)
        int w2 = t >> 5, T2 = (t >> 4) & 1, pt = t & 15;
        const float* P = x2p[w2][T2][pt];
        x2f[w2][T2][pt] = ((P[0] + P[1]) + (P[2] + P[3]))
                        + ((P[4] + P[5]) + (P[6] + P[7]));
    }
    __syncthreads();
    float x2x[2][4];
    #pragma unroll
    for (int T = 0; T < 2; ++T)
        #pragma unroll
        for (int r = 0; r < 4; ++r)
            x2x[T][r] = x2f[wv][T][q * 4 + r];

    float bd[2][4];
    int   bk[2][4];
    #pragma unroll
    for (int T = 0; T < 2; ++T)
        #pragma unroll
        for (int r = 0; r < 4; ++r) { bd[T][r] = 3.4e38f; bk[T][r] = 0; }

    // staging-chunk -> global address. chunk c (0..383): segment s=c>>6
    // (sp=s>>1 in {Ch,Cm,Cl}, kc=s&1), lane-in-seg l2=c&63 (row=l2&15,
    // q2=l2>>4). sp/kc are wave-uniform for c in {t, 256+t}.
    const unsigned short* const bases[3] = { Ch, Cm, Cl };
    #define CHUNK_GPTR(c, ct) ((const v8s*)(bases[(c) >> 7] +                 \
        ((size_t)((ct) * 16 + (((c) & 63) & 15)) * 64 +                       \
         (((c) >> 6) & 1) * 32 + (((c) & 63) >> 4) * 8)))

    // prologue: prefetch tile 0 into registers
    v8s r1 = *CHUNK_GPTR(t, 0);
    v8s r2;
    if (t < 128) r2 = *CHUNK_GPTR(256 + t, 0);

    v8s* const BtV = (v8s*)Bt;
    for (int ct = 0; ct < 32; ++ct) {
        __syncthreads();                 // all waves done reading Bt (prev)
        BtV[t] = r1;                     // ds_write forces vmcnt wait HERE
        if (t < 128) BtV[256 + t] = r2;
        if (ct < 31) {                   // prefetch ct+1 (in flight over GEMM)
            r1 = *CHUNK_GPTR(t, ct + 1);
            if (t < 128) r2 = *CHUNK_GPTR(256 + t, ct + 1);
        }
        __syncthreads();                 // Bt ready

        v8s bh0 = BtV[0 * 64 + l];
        v8s bh1 = BtV[1 * 64 + l];
        v8s bm0 = BtV[2 * 64 + l];
        v8s bm1 = BtV[3 * 64 + l];
        v8s bl0 = BtV[4 * 64 + l];
        v8s bl1 = BtV[5 * 64 + l];
        float c2k = c2t[ct * 16 + row];

        #pragma unroll
        for (int T = 0; T < 2; ++T) {
            v4f acc = {0.f, 0.f, 0.f, 0.f};
            acc = __builtin_amdgcn_mfma_f32_16x16x32_bf16(ah[T][0], bh0, acc, 0, 0, 0);
            acc = __builtin_amdgcn_mfma_f32_16x16x32_bf16(ah[T][1], bh1, acc, 0, 0, 0);
            acc = __builtin_amdgcn_mfma_f32_16x16x32_bf16(am[T][0], bh0, acc, 0, 0, 0);
            acc = __builtin_amdgcn_mfma_f32_16x16x32_bf16(am[T][1], bh1, acc, 0, 0, 0);
            acc = __builtin_amdgcn_mfma_f32_16x16x32_bf16(ah[T][0], bm0, acc, 0, 0, 0);
            acc = __builtin_amdgcn_mfma_f32_16x16x32_bf16(ah[T][1], bm1, acc, 0, 0, 0);
            acc = __builtin_amdgcn_mfma_f32_16x16x32_bf16(am[T][0], bm0, acc, 0, 0, 0);
            acc = __builtin_amdgcn_mfma_f32_16x16x32_bf16(am[T][1], bm1, acc, 0, 0, 0);
            acc = __builtin_amdgcn_mfma_f32_16x16x32_bf16(al[T][0], bh0, acc, 0, 0, 0);
            acc = __builtin_amdgcn_mfma_f32_16x16x32_bf16(al[T][1], bh1, acc, 0, 0, 0);
            acc = __builtin_amdgcn_mfma_f32_16x16x32_bf16(ah[T][0], bl0, acc, 0, 0, 0);
            acc = __builtin_amdgcn_mfma_f32_16x16x32_bf16(ah[T][1], bl1, acc, 0, 0, 0);
            #pragma unroll
            for (int r = 0; r < 4; ++r) {
                float tt = x2x[T][r] + c2k;
                float d2 = fmaf(-2.0f, acc[r], tt);
                if (d2 < bd[T][r]) { bd[T][r] = d2; bk[T][r] = ct * 16 + row; }
            }
        }
    }
    #undef CHUNK_GPTR

    // ---- cross-lane argmin over the 16 center residues (lane bits 0..3)
    #pragma unroll
    for (int T = 0; T < 2; ++T)
        #pragma unroll
        for (int r = 0; r < 4; ++r) {
            unsigned int b = __float_as_uint(bd[T][r]);
            b = (b & 0x80000000u) ? ~b : (b | 0x80000000u);
            unsigned long long key = ((unsigned long long)b << 32)
                                   | (unsigned int)bk[T][r];
            #pragma unroll
            for (int st = 1; st <= 8; st <<= 1) {
                unsigned long long o = __shfl_xor(key, st, 64);
                if (o < key) key = o;
            }
            if (row == 0) {
                int p = pbase + T * 16 + q * 4 + r;
                out_f[p] = (float)((int)(unsigned int)key);
            }
        }
}

// ---------------------------------------------------------------------------
// accumulate: 256 blocks = 64 chunks x 4 dim-slices. INT64 fixed-point LDS +
// global atomics (order-independent -> bit-deterministic, round-5 proven).
// ---------------------------------------------------------------------------
__global__ __launch_bounds__(256) void accum_kernel(
        const float* __restrict__ X, const float* __restrict__ af,
        unsigned long long* __restrict__ qsums, int* __restrict__ counts) {
    __shared__ unsigned long long lsum[KC * 16];   // 64 KB
    __shared__ int lcnt[KC];
    int slice = blockIdx.x & 3;
    int chunk = blockIdx.x >> 2;
    int p4 = threadIdx.x >> 2;
    int c4 = threadIdx.x & 3;

    for (int i = threadIdx.x; i < KC * 16; i += 256) lsum[i] = 0ull;
    for (int i = threadIdx.x; i < KC; i += 256) lcnt[i] = 0;
    __syncthreads();

    int base = chunk * CHUNK_PTS;
    #pragma unroll 2
    for (int it = 0; it < CHUNK_PTS / 64; ++it) {
        int n = base + it * 64 + p4;
        int a = (int)af[n];
        float4 xv = *(const float4*)(X + (size_t)n * DIM + slice * 16 + c4 * 4);
        long long q0 = (long long)llrint((double)xv.x * FIXSCALE);
        long long q1 = (long long)llrint((double)xv.y * FIXSCALE);
        long long q2 = (long long)llrint((double)xv.z * FIXSCALE);
        long long q3 = (long long)llrint((double)xv.w * FIXSCALE);
        atomicAdd(&lsum[a * 16 + c4 * 4 + 0], (unsigned long long)q0);
        atomicAdd(&lsum[a * 16 + c4 * 4 + 1], (unsigned long long)q1);
        atomicAdd(&lsum[a * 16 + c4 * 4 + 2], (unsigned long long)q2);
        atomicAdd(&lsum[a * 16 + c4 * 4 + 3], (unsigned long long)q3);
        if (slice == 0 && c4 == 0) atomicAdd(&lcnt[a], 1);
    }
    __syncthreads();

    for (int i = threadIdx.x; i < KC * 16; i += 256) {
        unsigned long long v = lsum[i];
        if (v != 0ull)
            atomicAdd(&qsums[(i >> 4) * DIM + slice * 16 + (i & 15)], v);
    }
    if (slice == 0)
        for (int i = threadIdx.x; i < KC; i += 256) {
            int v = lcnt[i];
            if (v != 0) atomicAdd(&counts[i], v);
        }
}

// ---------------------------------------------------------------------------
// update: centers = sums/max(cnt,1), ==0 -> re-seed; writes f32 centers to
// d_out tail, next iter's c2 (same butterfly tree) + 3-way bf16 splits.
// ---------------------------------------------------------------------------
__global__ __launch_bounds__(256) void update_kernel(
        const unsigned long long* __restrict__ qsums,
        const int* __restrict__ counts,
        const int* __restrict__ repl, const float* __restrict__ X,
        float* __restrict__ outC, float* __restrict__ c2v,
        unsigned short* __restrict__ Ch, unsigned short* __restrict__ Cm,
        unsigned short* __restrict__ Cl) {
    int k = blockIdx.x * 4 + (threadIdx.x >> 6);
    int d = threadIdx.x & 63;

    long long qq = (long long)qsums[k * DIM + d];
    float s = (float)((double)qq * (1.0 / FIXSCALE));
    float cnt = (float)counts[k];
    float v = s / fmaxf(cnt, 1.0f);
    if (v == 0.0f) v = X[(size_t)repl[k] * DIM + d];
    outC[k * DIM + d] = v;

    short h, m, l;
    split3(v, h, m, l);
    Ch[k * DIM + d] = (unsigned short)h;
    Cm[k * DIM + d] = (unsigned short)m;
    Cl[k * DIM + d] = (unsigned short)l;

    float sq = v * v;
    #pragma unroll
    for (int st = 1; st < 64; st <<= 1)
        sq += __shfl_xor(sq, st, 64);
    if (d == 0) c2v[k] = sq;
}

// ---------------------------------------------------------------------------
extern "C" void kernel_launch(void* const* d_in, const int* in_sizes, int n_in,
                              void* d_out, int out_size, void* d_ws, size_t ws_size,
                              hipStream_t stream) {
    const float* X    = (const float*)d_in[0];   // [N, D]
    const float* C0   = (const float*)d_in[1];   // [K, D]
    const int*   repl = (const int*)d_in[2];     // [MAXIT, K]
    float* out = (float*)d_out;                  // [N] assignments + [K*D] centers

    // ws: 452 KB total (round-2's 920 KB proved safe; round-3's 12.8 MB not).
    char* ws = (char*)d_ws;
    unsigned short* Ch = (unsigned short*)(ws + 0);            // 64 KB
    unsigned short* Cm = (unsigned short*)(ws + (64 << 10));   // 64 KB
    unsigned short* Cl = (unsigned short*)(ws + (128 << 10));  // 64 KB
    unsigned long long* qsums = (unsigned long long*)(ws + (192 << 10)); // 256 KB
    int*   counts = (int*)  (ws + (448 << 10));                // 2 KB
    float* c2v    = (float*)(ws + (450 << 10));                // 2 KB

    prep_kernel<<<2, 256, 0, stream>>>(C0, c2v, Ch, Cm, Cl);

    for (int i = 0; i < MAXIT; ++i) {
        assign_kernel<<<N_PTS / 128, 256, 0, stream>>>(
            X, Ch, Cm, Cl, c2v, out);

        hipMemsetAsync(qsums, 0, KC * DIM * sizeof(unsigned long long)
                                 + KC * sizeof(int), stream);

        accum_kernel<<<NCHUNK * 4, 256, 0, stream>>>(X, out, qsums, counts);

        update_kernel<<<KC / 4, 256, 0, stream>>>(
            qsums, counts, repl + i * KC, X, out + N_PTS, c2v, Ch, Cm, Cl);
    }
}